// Round 11
// baseline (254.385 us; speedup 1.0000x reference)
//
#include <hip/hip_runtime.h>
#include <stdint.h>

#pragma clang fp contract(off)

#define NCELL 49
#define NCLS  20
#define NSEG  16
#define MAGIC 0x5A5A5A5Au

struct Box { float x1, y1, x2, y2; };

// Bit-exact branchless sigmoid (see R9 note): z identical in both branches,
// numerator select reproduces the reference's two-sided form exactly.
__device__ __forceinline__ float sigmoid_ref(float x) {
#pragma clang fp contract(off)
  float z = expf(-fabsf(x));
  float num = (x >= 0.0f) ? 1.0f : z;
  return num / (1.0f + z);
}

__device__ __forceinline__ float iou_box(Box a, Box b) {
#pragma clang fp contract(off)
  float lx = fmaxf(a.x1, b.x1);
  float ly = fmaxf(a.y1, b.y1);
  float rx = fminf(a.x2, b.x2);
  float ry = fminf(a.y2, b.y2);
  float w = fmaxf(rx - lx, 0.0f);
  float h = fmaxf(ry - ly, 0.0f);
  float inter = w * h;
  float aa = (a.x2 - a.x1) * (a.y2 - a.y1);
  float ab = (b.x2 - b.x1) * (b.y2 - b.y1);
  return inter / (aa + ab - inter);
}

__device__ __forceinline__ unsigned mbcnt64(unsigned long long m) {
  return __builtin_amdgcn_mbcnt_hi((unsigned)(m >> 32),
         __builtin_amdgcn_mbcnt_lo((unsigned)m, 0u));
}
#define WSYNC() __builtin_amdgcn_wave_barrier()

__device__ __forceinline__ unsigned match_mask(unsigned w, unsigned wantx4) {
  unsigned y = (w & 0x3f3f3f3fu) ^ wantx4;
  return ~(y + 0x7f7f7f7fu) & 0x80808080u;
}

__device__ __forceinline__ uint4 load_tile(const uint8_t* entries, int e, int e1, int ne) {
  uint4 w4 = make_uint4(0, 0, 0, 0);
  if (e < e1) {
    int p = e << 4;
    if (p + 16 <= ne) {
      w4 = *(const uint4*)(entries + p);
    } else {
      unsigned ws[4] = {0, 0, 0, 0};
      for (int k = 0; k < ne - p; ++k)
        ws[k >> 2] |= ((unsigned)entries[p + k]) << (8 * (k & 3));
      w4.x = ws[0]; w4.y = ws[1]; w4.z = ws[2]; w4.w = ws[3];
    }
  }
  return w4;
}

// Single fused kernel. Phase 1: per-image (1 wave each, 4/block) decode +
// NMS + TP, entries bytes + unconditional per-image stats slots (no atomics,
// no pre-zeroed memory). Grid barrier via flag array — SAFE BY CAPACITY:
// grid = ceil(batch/4) <= 1024 <= chip residency at this kernel's resources.
// Phase 2: first 320 blocks take (class,segment) AP-scan roles; block 0
// finishes with the exact R10-ordered final reduction.
__global__ __launch_bounds__(256) void k_all(
    const float* __restrict__ target, const float* __restrict__ output,
    uint8_t* __restrict__ entries, unsigned* __restrict__ stats,
    unsigned* __restrict__ flags1, unsigned* __restrict__ flags2,
    unsigned* __restrict__ gts, double* __restrict__ partials,
    float* __restrict__ out, int batch, int segimg)
{
#pragma clang fp contract(off)
  __shared__ float4 pbox[4][64];
  __shared__ int2   pcc [4][64];
  __shared__ float4 gbox[4][64];
  __shared__ int    gcv [4][64];
  __shared__ float  ctab[4][64];
  __shared__ float2 mtab[4][64];
  __shared__ unsigned long long wt[4];
  __shared__ unsigned long long redA[4];
  __shared__ double wacc[4];
  __shared__ float  apf[NCLS];

  int tid = threadIdx.x;
  int lane = tid & 63;
  int w = tid >> 6;
  int img = blockIdx.x * 4 + w;

  // ================= phase 1: per-image =================
  if (img < batch) {
    bool a = lane < NCELL;
    float tv[30], ov[30];
    if (a) {
      const float2* T2 = (const float2*)(target + (size_t)img * 1470 + lane * 30);
      const float2* O2 = (const float2*)(output + (size_t)img * 1470 + lane * 30);
#pragma unroll
      for (int i = 0; i < 15; ++i) { float2 t = T2[i]; tv[2*i] = t.x; tv[2*i+1] = t.y; }
#pragma unroll
      for (int i = 0; i < 15; ++i) { float2 o = O2[i]; ov[2*i] = o.x; ov[2*i+1] = o.y; }
    } else {
#pragma unroll
      for (int i = 0; i < 30; ++i) { tv[i] = 0.0f; ov[i] = 0.0f; }
    }

    float fjx = (float)(lane % 7), fiy = (float)(lane / 7);

    // ---- ground truth ----
    int gcls = 0; bool gval = false;
    {
      float tbv = tv[10];
#pragma unroll
      for (int c = 1; c < NCLS; ++c) { float v = tv[10 + c]; if (v > tbv) { tbv = v; gcls = c; } }
      gval = a && (tv[4] > 0.5f);
      float cx = (tv[0] + fjx) * 64.0f, cy = (tv[1] + fiy) * 64.0f;
      float w2 = tv[2] * 448.0f, h2 = tv[3] * 448.0f;
      gbox[w][lane] = make_float4(cx - w2 * 0.5f, cy - h2 * 0.5f,
                                  cx + w2 * 0.5f, cy + h2 * 0.5f);
      gcv[w][lane] = gcls | (gval ? 256 : 0);
    }

    // ---- predictions: 26 sigmoids (selection commutes with sigmoid) ----
    float myc = -1.0f; int myk = 0; float px1 = 0, py1 = 0, px2 = 0, py2 = 0;
    if (a) {
      float s0 = sigmoid_ref(ov[4]);
      float s1 = sigmoid_ref(ov[9]);
      myc = fmaxf(s0, s1);
      int resp = (s1 > s0) ? 1 : 0;    // first max wins, sigmoid-space compare
      float x  = sigmoid_ref(ov[resp * 5 + 0]);
      float y  = sigmoid_ref(ov[resp * 5 + 1]);
      float ww = sigmoid_ref(ov[resp * 5 + 2]);
      float hh = sigmoid_ref(ov[resp * 5 + 3]);
      float obv = sigmoid_ref(ov[10]); myk = 0;
#pragma unroll
      for (int c = 1; c < NCLS; ++c) {
        float v = sigmoid_ref(ov[10 + c]);
        if (v > obv) { obv = v; myk = c; }
      }
      float cx = (x + fjx) * 64.0f, cy = (y + fiy) * 64.0f;
      float W = ww * 448.0f, H = hh * 448.0f;
      px1 = cx - W * 0.5f; py1 = cy - H * 0.5f;
      px2 = cx + W * 0.5f; py2 = cy + H * 0.5f;
    }
    ctab[w][lane] = myc;
    WSYNC();

    // ---- stable rank via broadcast LDS reads ----
    int r = 0;
#pragma unroll
    for (int j = 0; j < NCELL; ++j) {
      float cj = ctab[w][j];
      r += (cj > myc) || (cj == myc && j < lane);
    }
    r = a ? r : lane;

    pbox[w][r] = make_float4(px1, py1, px2, py2);
    pcc[w][r]  = make_int2(myk, __float_as_int(myc));
    WSYNC();

    float4 sb4 = pbox[w][lane];
    int2   cc  = pcc[w][lane];
    Box myS; myS.x1 = sb4.x; myS.y1 = sb4.y; myS.x2 = sb4.z; myS.y2 = sb4.w;
    int scls = cc.x;
    float sconf = __int_as_float(cc.y);

    // ---- NMS candidate mask (full unroll, dependence-free) ----
    unsigned long long candmask = 0;
#pragma unroll
    for (int i = 0; i < NCELL; ++i) {
      float4 b4 = pbox[w][i];
      int ki = pcc[w][i].x;
      Box bi; bi.x1 = b4.x; bi.y1 = b4.y; bi.x2 = b4.z; bi.y2 = b4.w;
      float v = iou_box(myS, bi);
      bool s = a && (lane > i) && (scls == ki) && (v > 0.5f);
      candmask |= s ? (1ull << i) : 0ull;
    }

    // ---- NMS serial resolve (branch-free select chain) ----
    unsigned long long sup = 0;
#pragma unroll
    for (int i = 0; i < NCELL; ++i) {
      unsigned long long bi = __ballot(((candmask >> i) & 1ull) != 0ull);
      bool keep = ((sup >> i) & 1ull) == 0ull;
      sup |= keep ? bi : 0ull;
    }

    bool vp = a && !((sup >> lane) & 1ull) && (sconf > 0.5f);

    // ---- best same-class GT per pred ----
    float mx = -1.0f; int best = 0;
#pragma unroll
    for (int g = 0; g < NCELL; ++g) {
      float4 b4 = gbox[w][g];
      int cv = gcv[w][g];
      Box bg; bg.x1 = b4.x; bg.y1 = b4.y; bg.x2 = b4.z; bg.y2 = b4.w;
      float v = iou_box(myS, bg);
      bool upd = a && (cv & 256) && (scls == (cv & 255)) && (v > mx);
      mx = upd ? v : mx;
      best = upd ? g : best;
    }
    mtab[w][lane] = make_float2(mx, __int_as_float(best));
    WSYNC();

    // ---- greedy TP assignment ----
    unsigned long long vpmask = __ballot(vp);
    unsigned long long matched = 0, hits = 0;
#pragma unroll 7
    for (int i = 0; i < NCELL; ++i) {
      float2 f2 = mtab[w][i];
      float mxi = f2.x;
      int bi = __float_as_int(f2.y);
      bool hit = ((vpmask >> i) & 1ull) && (mxi > 0.5f) && !((matched >> bi) & 1ull);
      matched |= hit ? (1ull << bi) : 0ull;
      hits    |= hit ? (1ull << i)  : 0ull;
    }

    if (a) {
      entries[(size_t)img * NCELL + lane] =
          (uint8_t)(scls | (vp ? 32 : 0) | (((hits >> lane) & 1ull) ? 64 : 0));
    }

    // ---- per-image per-class stats slot (unconditional; no atomics) ----
    {
      int gcnt = 0; unsigned vcnt = 0, tcnt = 0;
#pragma unroll 1
      for (int c = 0; c < NCLS; ++c) {
        unsigned long long gm = __ballot(gval && (gcls == c));
        unsigned long long pm = __ballot(a && (scls == c));
        if (lane == c) {
          gcnt = (int)__popcll(gm);
          vcnt = (unsigned)__popcll(pm & vpmask);
          tcnt = (unsigned)__popcll(pm & hits);
        }
      }
      if (lane < NCLS) {
        stats[(size_t)img * NCLS + lane] =
            ((unsigned)gcnt << 20) | (vcnt << 10) | tcnt;
      }
    }
  }

  // ================= grid barrier (capacity-guaranteed residency) ==========
  __threadfence();
  __syncthreads();
  if (tid == 0)
    __hip_atomic_store(&flags1[blockIdx.x], MAGIC,
                       __ATOMIC_RELAXED, __HIP_MEMORY_SCOPE_AGENT);
  if (tid < 64) {
    int nb = (int)gridDim.x;
    for (;;) {
      bool ok = true;
      for (int i = lane; i < nb; i += 64)
        ok &= (__hip_atomic_load(&flags1[i], __ATOMIC_RELAXED,
                                 __HIP_MEMORY_SCOPE_AGENT) == MAGIC);
      if (__ballot(ok) == ~0ull) break;
      __builtin_amdgcn_s_sleep(2);
    }
  }
  __syncthreads();
  __threadfence();

  if (blockIdx.x >= NCLS * NSEG) return;

  // ================= phase 2: (class, segment) AP scan =====================
  int c = blockIdx.x / NSEG, s = blockIdx.x % NSEG;
  int ne = batch * NCELL;
  unsigned wantx4 = (32u + (unsigned)c) * 0x01010101u;

  // gt_count[c] over all images + (valid,tp) prefix over images < s*segimg
  unsigned long long packA = 0;   // g<<42 | v<<21 | t  (each sum < 2^21)
  {
    int pre = s * segimg;
    for (int i = tid; i < batch; i += 256) {
      unsigned x = stats[(size_t)i * NCLS + c];
      packA += ((unsigned long long)(x >> 20) << 42);
      if (i < pre)
        packA += ((unsigned long long)((x >> 10) & 1023u) << 21) |
                 (unsigned long long)(x & 1023u);
    }
#pragma unroll
    for (int d = 1; d < 64; d <<= 1) packA += __shfl_xor(packA, d, 64);
    if (lane == 0) redA[w] = packA;
    __syncthreads();
    packA = redA[0] + redA[1] + redA[2] + redA[3];
  }
  unsigned gAll = (unsigned)(packA >> 42);
  unsigned Jrun = (unsigned)((packA >> 21) & 0x1FFFFFull);
  unsigned Trun = (unsigned)(packA & 0x1FFFFFull);
  float g2 = (float)(int)gAll + 1e-6f;
  if (s == 0 && tid == 0) gts[c] = gAll;

  int nel = (ne + 15) >> 4;
  int segel = segimg * NCELL / 16;
  int se0 = s * segel; if (se0 > nel) se0 = nel;
  int se1 = se0 + segel; if (se1 > nel) se1 = nel;
  int elw = (se1 > se0) ? ((se1 - se0 + 3) >> 2) : 0;
  int e0 = se0 + w * elw; if (e0 > se1) e0 = se1;
  int e1 = e0 + elw; if (e1 > se1) e1 = se1;
  int ntile = (e1 > e0) ? ((e1 - e0 + 63) >> 6) : 0;

  // local phase A: per-wave totals within segment
  unsigned mv = 0, mt = 0;
  for (int t = 0; t < ntile; ++t) {
    uint4 w4 = load_tile(entries, e0 + t * 64 + lane, e1, ne);
    unsigned wsv[4] = {w4.x, w4.y, w4.z, w4.w};
#pragma unroll
    for (int q = 0; q < 4; ++q) {
      unsigned m = match_mask(wsv[q], wantx4);
      mv += __popc(m);
      mt += __popc(m & (wsv[q] << 1));
    }
  }
  unsigned long long tot = ((unsigned long long)mv << 32) | (unsigned long long)mt;
#pragma unroll
  for (int d = 1; d < 64; d <<= 1) tot += __shfl_xor(tot, d, 64);
  if (lane == 0) wt[w] = tot;
  __syncthreads();
  for (int w2 = 0; w2 < w; ++w2) {
    Jrun += (unsigned)(wt[w2] >> 32);
    Trun += (unsigned)(wt[w2] & 0xffffffffull);
  }

  // phase B: per-tile bit-plane prefix + sparse emit
  double acc = 0.0;
  for (int t = 0; t < ntile; ++t) {
    int e = e0 + t * 64 + lane;
    int p = e << 4;
    uint4 w4 = load_tile(entries, e, e1, ne);
    unsigned wsv[4] = {w4.x, w4.y, w4.z, w4.w};
    unsigned mm[4], tm[4];
    unsigned cv = 0, ct = 0;
#pragma unroll
    for (int q = 0; q < 4; ++q) {
      unsigned m = match_mask(wsv[q], wantx4);
      mm[q] = m; tm[q] = m & (wsv[q] << 1);
      cv += __popc(m); ct += __popc(tm[q]);
    }
    unsigned jexcl = 0, texcl = 0, jtt = 0, ttt = 0;
#pragma unroll
    for (int b = 0; b < 5; ++b) {
      unsigned long long mj = __ballot(((cv >> b) & 1u) != 0u);
      unsigned long long mk = __ballot(((ct >> b) & 1u) != 0u);
      jexcl += mbcnt64(mj) << b;
      texcl += mbcnt64(mk) << b;
      jtt   += (unsigned)__popcll(mj) << b;
      ttt   += (unsigned)__popcll(mk) << b;
    }
    unsigned jr = Jrun + jexcl;
    unsigned tr = Trun + texcl;
#pragma unroll
    for (int q = 0; q < 4; ++q) {
      unsigned m = mm[q];
      while (m) {
        unsigned bit = (unsigned)__builtin_ctz(m);
        m &= m - 1;
        ++jr;
        if (tm[q] & (1u << bit)) {
          ++tr;
          int pos = p + 4 * q + (int)(bit >> 3);
          float ft = (float)tr, fj = (float)jr;
          float r_cur  = ft / g2;
          float r_prev = (ft - 1.0f) / g2;
          float p_cur  = ft / (fj + 1e-6f);
          float p_prev = (pos == 0) ? 1.0f
                                    : (ft - 1.0f) / ((fj - 1.0f) + 1e-6f);
          acc += (double)((r_cur - r_prev) * (p_cur + p_prev) * 0.5f);
        }
      }
    }
    Jrun += jtt;
    Trun += ttt;
  }

  for (int d = 32; d > 0; d >>= 1) acc += __shfl_down(acc, d, 64);
  if (lane == 0) wacc[w] = acc;
  __syncthreads();
  if (tid == 0) {
    partials[blockIdx.x] = wacc[0] + wacc[1] + wacc[2] + wacc[3];
  }
  __threadfence();
  __syncthreads();
  if (tid == 0)
    __hip_atomic_store(&flags2[blockIdx.x], MAGIC,
                       __ATOMIC_RELAXED, __HIP_MEMORY_SCOPE_AGENT);

  // ================= final reduction on block 0 ============================
  if (blockIdx.x == 0) {
    if (tid < 64) {
      for (;;) {
        bool ok = true;
        for (int i = lane; i < NCLS * NSEG; i += 64)
          ok &= (__hip_atomic_load(&flags2[i], __ATOMIC_RELAXED,
                                   __HIP_MEMORY_SCOPE_AGENT) == MAGIC);
        if (__ballot(ok) == ~0ull) break;
        __builtin_amdgcn_s_sleep(2);
      }
    }
    __syncthreads();
    __threadfence();
    if (tid < NCLS) {
      double d2 = 0.0;
#pragma unroll
      for (int s2 = 0; s2 < NSEG; ++s2) d2 += partials[tid * NSEG + s2];
      apf[tid] = (float)d2;
    }
    __syncthreads();
    if (tid == 0) {
      float sf = 0.0f, nf = 0.0f;
      for (int cc = 0; cc < NCLS; ++cc)
        if (gts[cc] > 0u) { sf += apf[cc]; nf += 1.0f; }
      out[0] = sf / fmaxf(nf, 1.0f);
    }
  }
}

extern "C" void kernel_launch(void* const* d_in, const int* in_sizes, int n_in,
                              void* d_out, int out_size, void* d_ws, size_t ws_size,
                              hipStream_t stream) {
  const float* target = (const float*)d_in[0];
  const float* output = (const float*)d_in[1];
  int batch = in_sizes[0] / (NCELL * 30);
  int ne = batch * NCELL;
  int segimg = (((batch + NSEG - 1) / NSEG) + 15) & ~15;  // 16-image aligned
  int gridB = (batch + 3) / 4;

  char* p = (char*)d_ws;
  uint8_t*  entries  = (uint8_t*)p;
  size_t off = ((size_t)ne + 255) & ~(size_t)255;
  unsigned* stats    = (unsigned*)(p + off);               // batch*20*4
  size_t off2 = off + (((size_t)batch * NCLS * 4 + 255) & ~(size_t)255);
  unsigned* flags1   = (unsigned*)(p + off2);              // gridB*4
  size_t off3 = off2 + (((size_t)gridB * 4 + 255) & ~(size_t)255);
  unsigned* flags2   = (unsigned*)(p + off3);              // 320*4
  size_t off4 = off3 + 2048;
  unsigned* gts      = (unsigned*)(p + off4);              // 20*4
  size_t off5 = off4 + 256;
  double*   partials = (double*)(p + off5);                // 320*8

  k_all<<<gridB, 256, 0, stream>>>(
      target, output, entries, stats, flags1, flags2, gts, partials,
      (float*)d_out, batch, segimg);
}

// Round 12
// 190.628 us; speedup vs baseline: 1.3345x; 1.3345x over previous
//
#include <hip/hip_runtime.h>
#include <stdint.h>

#pragma clang fp contract(off)

#define NCELL 49
#define NCLS  20
#define NSEG  64

struct Box { float x1, y1, x2, y2; };

// Bit-exact branchless sigmoid (see R9 note).
__device__ __forceinline__ float sigmoid_ref(float x) {
#pragma clang fp contract(off)
  float z = expf(-fabsf(x));
  float num = (x >= 0.0f) ? 1.0f : z;
  return num / (1.0f + z);
}

__device__ __forceinline__ float iou_box(Box a, Box b) {
#pragma clang fp contract(off)
  float lx = fmaxf(a.x1, b.x1);
  float ly = fmaxf(a.y1, b.y1);
  float rx = fminf(a.x2, b.x2);
  float ry = fminf(a.y2, b.y2);
  float w = fmaxf(rx - lx, 0.0f);
  float h = fmaxf(ry - ly, 0.0f);
  float inter = w * h;
  float aa = (a.x2 - a.x1) * (a.y2 - a.y1);
  float ab = (b.x2 - b.x1) * (b.y2 - b.y1);
  return inter / (aa + ab - inter);
}

__device__ __forceinline__ unsigned mbcnt64(unsigned long long m) {
  return __builtin_amdgcn_mbcnt_hi((unsigned)(m >> 32),
         __builtin_amdgcn_mbcnt_lo((unsigned)m, 0u));
}
#define WSYNC() __builtin_amdgcn_wave_barrier()

// One wave per image; 4 waves/block; R10's structure (best measured 76 us)
// with the bit-exact 26-sigmoid selection.
__global__ __launch_bounds__(256) void k_per_image(
    const float* __restrict__ target, const float* __restrict__ output,
    uint8_t* __restrict__ entries, int* __restrict__ gt_count,
    unsigned* __restrict__ totals, int batch, int segimg)
{
#pragma clang fp contract(off)
  __shared__ float4 pbox[4][64];
  __shared__ int2   pcc [4][64];
  __shared__ float4 gbox[4][64];
  __shared__ int    gcv [4][64];
  __shared__ float  ctab[4][64];
  __shared__ float2 mtab[4][64];

  int tid = threadIdx.x;
  int lane = tid & 63;
  int w = tid >> 6;
  int img = blockIdx.x * 4 + w;
  if (img >= batch) return;          // uniform per wave
  bool a = lane < NCELL;

  float tv[30], ov[30];
  if (a) {
    const float2* T2 = (const float2*)(target + (size_t)img * 1470 + lane * 30);
    const float2* O2 = (const float2*)(output + (size_t)img * 1470 + lane * 30);
#pragma unroll
    for (int i = 0; i < 15; ++i) { float2 t = T2[i]; tv[2*i] = t.x; tv[2*i+1] = t.y; }
#pragma unroll
    for (int i = 0; i < 15; ++i) { float2 o = O2[i]; ov[2*i] = o.x; ov[2*i+1] = o.y; }
  } else {
#pragma unroll
    for (int i = 0; i < 30; ++i) { tv[i] = 0.0f; ov[i] = 0.0f; }
  }

  float fjx = (float)(lane % 7), fiy = (float)(lane / 7);

  // ---- ground truth ----
  int gcls = 0; bool gval = false;
  {
    float tbv = tv[10];
#pragma unroll
    for (int c = 1; c < NCLS; ++c) { float v = tv[10 + c]; if (v > tbv) { tbv = v; gcls = c; } }
    gval = a && (tv[4] > 0.5f);
    float cx = (tv[0] + fjx) * 64.0f, cy = (tv[1] + fiy) * 64.0f;
    float w2 = tv[2] * 448.0f, h2 = tv[3] * 448.0f;
    gbox[w][lane] = make_float4(cx - w2 * 0.5f, cy - h2 * 0.5f,
                                cx + w2 * 0.5f, cy + h2 * 0.5f);
    gcv[w][lane] = gcls | (gval ? 256 : 0);
  }

  // ---- predictions: 26 sigmoids (selection commutes; bit-exact) ----
  float myc = -1.0f; int myk = 0; float px1 = 0, py1 = 0, px2 = 0, py2 = 0;
  if (a) {
    float s0 = sigmoid_ref(ov[4]);
    float s1 = sigmoid_ref(ov[9]);
    myc = fmaxf(s0, s1);
    int resp = (s1 > s0) ? 1 : 0;
    float x  = sigmoid_ref(ov[resp * 5 + 0]);
    float y  = sigmoid_ref(ov[resp * 5 + 1]);
    float ww = sigmoid_ref(ov[resp * 5 + 2]);
    float hh = sigmoid_ref(ov[resp * 5 + 3]);
    float obv = sigmoid_ref(ov[10]); myk = 0;
#pragma unroll
    for (int c = 1; c < NCLS; ++c) {
      float v = sigmoid_ref(ov[10 + c]);
      if (v > obv) { obv = v; myk = c; }
    }
    float cx = (x + fjx) * 64.0f, cy = (y + fiy) * 64.0f;
    float W = ww * 448.0f, H = hh * 448.0f;
    px1 = cx - W * 0.5f; py1 = cy - H * 0.5f;
    px2 = cx + W * 0.5f; py2 = cy + H * 0.5f;
  }
  ctab[w][lane] = myc;
  WSYNC();

  // ---- stable rank via broadcast LDS reads ----
  int r = 0;
#pragma unroll
  for (int j = 0; j < NCELL; ++j) {
    float cj = ctab[w][j];
    r += (cj > myc) || (cj == myc && j < lane);
  }
  r = a ? r : lane;

  pbox[w][r] = make_float4(px1, py1, px2, py2);
  pcc[w][r]  = make_int2(myk, __float_as_int(myc));
  WSYNC();

  float4 sb4 = pbox[w][lane];
  int2   cc  = pcc[w][lane];
  Box myS; myS.x1 = sb4.x; myS.y1 = sb4.y; myS.x2 = sb4.z; myS.y2 = sb4.w;
  int scls = cc.x;
  float sconf = __int_as_float(cc.y);

  // ---- NMS candidate mask (full unroll, dependence-free) ----
  unsigned long long candmask = 0;
#pragma unroll
  for (int i = 0; i < NCELL; ++i) {
    float4 b4 = pbox[w][i];
    int ki = pcc[w][i].x;
    Box bi; bi.x1 = b4.x; bi.y1 = b4.y; bi.x2 = b4.z; bi.y2 = b4.w;
    float v = iou_box(myS, bi);
    bool s = a && (lane > i) && (scls == ki) && (v > 0.5f);
    candmask |= s ? (1ull << i) : 0ull;
  }

  // ---- NMS serial resolve (branch-free select chain) ----
  unsigned long long sup = 0;
#pragma unroll
  for (int i = 0; i < NCELL; ++i) {
    unsigned long long bi = __ballot(((candmask >> i) & 1ull) != 0ull);
    bool keep = ((sup >> i) & 1ull) == 0ull;
    sup |= keep ? bi : 0ull;
  }

  bool vp = a && !((sup >> lane) & 1ull) && (sconf > 0.5f);

  // ---- best same-class GT per pred ----
  float mx = -1.0f; int best = 0;
#pragma unroll
  for (int g = 0; g < NCELL; ++g) {
    float4 b4 = gbox[w][g];
    int cv = gcv[w][g];
    Box bg; bg.x1 = b4.x; bg.y1 = b4.y; bg.x2 = b4.z; bg.y2 = b4.w;
    float v = iou_box(myS, bg);
    bool upd = a && (cv & 256) && (scls == (cv & 255)) && (v > mx);
    mx = upd ? v : mx;
    best = upd ? g : best;
  }
  mtab[w][lane] = make_float2(mx, __int_as_float(best));
  WSYNC();

  // ---- greedy TP assignment ----
  unsigned long long vpmask = __ballot(vp);
  unsigned long long matched = 0, hits = 0;
#pragma unroll 7
  for (int i = 0; i < NCELL; ++i) {
    float2 f2 = mtab[w][i];
    float mxi = f2.x;
    int bi = __float_as_int(f2.y);
    bool hit = ((vpmask >> i) & 1ull) && (mxi > 0.5f) && !((matched >> bi) & 1ull);
    matched |= hit ? (1ull << bi) : 0ull;
    hits    |= hit ? (1ull << i)  : 0ull;
  }

  if (a) {
    entries[(size_t)img * NCELL + lane] =
        (uint8_t)(scls | (vp ? 32 : 0) | (((hits >> lane) & 1ull) ? 64 : 0));
  }

  // ---- per-class stats: gt_count + packed (valid,tp) totals per segment ----
  {
    int seg = img / segimg;
    int gcnt = 0; unsigned pkt = 0;
#pragma unroll 1
    for (int c = 0; c < NCLS; ++c) {
      unsigned long long gm = __ballot(gval && (gcls == c));
      unsigned long long pm = __ballot(a && (scls == c));
      if (lane == c) {
        gcnt = (int)__popcll(gm);
        pkt  = ((unsigned)__popcll(pm & vpmask) << 16) |
                (unsigned)__popcll(pm & hits);
      }
    }
    if (lane < NCLS) {
      if (gcnt) atomicAdd(&gt_count[lane], gcnt);
      if (pkt)  atomicAdd(&totals[seg * 32 + lane], pkt);   // 2 lines/op
    }
  }
}

__device__ __forceinline__ unsigned match_mask(unsigned w, unsigned wantx4) {
  unsigned y = (w & 0x3f3f3f3fu) ^ wantx4;
  return ~(y + 0x7f7f7f7fu) & 0x80808080u;
}

__device__ __forceinline__ uint4 load_tile(const uint8_t* entries, int e, int e1, int ne) {
  uint4 w4 = make_uint4(0, 0, 0, 0);
  if (e < e1) {
    int p = e << 4;
    if (p + 16 <= ne) {
      w4 = *(const uint4*)(entries + p);
    } else {
      unsigned ws[4] = {0, 0, 0, 0};
      for (int k = 0; k < ne - p; ++k)
        ws[k >> 2] |= ((unsigned)entries[p + k]) << (8 * (k & 3));
      w4.x = ws[0]; w4.y = ws[1]; w4.z = ws[2]; w4.w = ws[3];
    }
  }
  return w4;
}

// One block per (class, segment); NSEG=64 -> 1280 blocks, ntile == 1 per
// wave (serial tile chain eliminated). Totals prefix is lane-parallel.
// Last block (fenced counter) does the final AP mean in-place.
__global__ __launch_bounds__(256) void k_apB(
    const uint8_t* __restrict__ entries, const unsigned* __restrict__ totals,
    const int* __restrict__ gt_count, double* __restrict__ partials,
    unsigned* __restrict__ counter, float* __restrict__ out,
    int ne, int segimg)
{
#pragma clang fp contract(off)
  int c = blockIdx.x / NSEG, s = blockIdx.x % NSEG;
  int tid = threadIdx.x, wid = tid >> 6, lane = tid & 63;
  float g2 = (float)gt_count[c] + 1e-6f;
  unsigned wantx4 = (32u + (unsigned)c) * 0x01010101u;

  int nel = (ne + 15) >> 4;
  int segel = segimg * NCELL / 16;     // segimg % 16 == 0 -> exact
  int se0 = s * segel; if (se0 > nel) se0 = nel;
  int se1 = se0 + segel; if (se1 > nel) se1 = nel;
  int elw = (se1 > se0) ? ((se1 - se0 + 3) >> 2) : 0;
  int e0 = se0 + wid * elw; if (e0 > se1) e0 = se1;
  int e1 = e0 + elw; if (e1 > se1) e1 = se1;
  int ntile = (e1 > e0) ? ((e1 - e0 + 63) >> 6) : 0;

  // ---- global prefix: lane-parallel load + wave reduce (exact ints) ----
  unsigned long long pk = 0;
  if (lane < s) {
    unsigned t2 = totals[lane * 32 + c];
    pk = ((unsigned long long)(t2 >> 16) << 32) | (unsigned long long)(t2 & 0xffffu);
  }
#pragma unroll
  for (int d = 1; d < 64; d <<= 1) pk += __shfl_xor(pk, d, 64);
  unsigned Jrun = (unsigned)(pk >> 32), Trun = (unsigned)(pk & 0xffffffffull);

  // local phase A: per-wave totals within segment -> wave offsets
  unsigned mv = 0, mt = 0;
  for (int t = 0; t < ntile; ++t) {
    uint4 w4 = load_tile(entries, e0 + t * 64 + lane, e1, ne);
    unsigned wsv[4] = {w4.x, w4.y, w4.z, w4.w};
#pragma unroll
    for (int q = 0; q < 4; ++q) {
      unsigned m = match_mask(wsv[q], wantx4);
      mv += __popc(m);
      mt += __popc(m & (wsv[q] << 1));
    }
  }
  unsigned long long tot = ((unsigned long long)mv << 32) | (unsigned long long)mt;
#pragma unroll
  for (int d = 1; d < 64; d <<= 1) tot += __shfl_xor(tot, d, 64);
  __shared__ unsigned long long wt[4];
  __shared__ double wacc[4];
  __shared__ int islast;
  __shared__ float apf_s[NCLS];
  if (lane == 0) wt[wid] = tot;
  __syncthreads();
  for (int w2 = 0; w2 < wid; ++w2) {
    Jrun += (unsigned)(wt[w2] >> 32);
    Trun += (unsigned)(wt[w2] & 0xffffffffull);
  }

  // phase B: per-tile bit-plane prefix + sparse emit
  double acc = 0.0;
  for (int t = 0; t < ntile; ++t) {
    int e = e0 + t * 64 + lane;
    int p = e << 4;
    uint4 w4 = load_tile(entries, e, e1, ne);
    unsigned wsv[4] = {w4.x, w4.y, w4.z, w4.w};
    unsigned mm[4], tm[4];
    unsigned cv = 0, ct = 0;
#pragma unroll
    for (int q = 0; q < 4; ++q) {
      unsigned m = match_mask(wsv[q], wantx4);
      mm[q] = m; tm[q] = m & (wsv[q] << 1);
      cv += __popc(m); ct += __popc(tm[q]);
    }
    unsigned jexcl = 0, texcl = 0, jtt = 0, ttt = 0;
#pragma unroll
    for (int b = 0; b < 5; ++b) {
      unsigned long long mj = __ballot(((cv >> b) & 1u) != 0u);
      unsigned long long mk = __ballot(((ct >> b) & 1u) != 0u);
      jexcl += mbcnt64(mj) << b;
      texcl += mbcnt64(mk) << b;
      jtt   += (unsigned)__popcll(mj) << b;
      ttt   += (unsigned)__popcll(mk) << b;
    }
    unsigned jr = Jrun + jexcl;
    unsigned tr = Trun + texcl;
#pragma unroll
    for (int q = 0; q < 4; ++q) {
      unsigned m = mm[q];
      while (m) {
        unsigned bit = (unsigned)__builtin_ctz(m);
        m &= m - 1;
        ++jr;
        if (tm[q] & (1u << bit)) {
          ++tr;
          int pos = p + 4 * q + (int)(bit >> 3);
          float ft = (float)tr, fj = (float)jr;
          float r_cur  = ft / g2;
          float r_prev = (ft - 1.0f) / g2;
          float p_cur  = ft / (fj + 1e-6f);
          float p_prev = (pos == 0) ? 1.0f
                                    : (ft - 1.0f) / ((fj - 1.0f) + 1e-6f);
          acc += (double)((r_cur - r_prev) * (p_cur + p_prev) * 0.5f);
        }
      }
    }
    Jrun += jtt;
    Trun += ttt;
  }

  for (int d = 32; d > 0; d >>= 1) acc += __shfl_down(acc, d, 64);
  if (lane == 0) wacc[wid] = acc;
  __syncthreads();
  if (tid == 0) {
    double bp = wacc[0] + wacc[1] + wacc[2] + wacc[3];
    __hip_atomic_store(&partials[blockIdx.x], bp,
                       __ATOMIC_RELEASE, __HIP_MEMORY_SCOPE_AGENT);
    unsigned prev = __hip_atomic_fetch_add(counter, 1u,
                       __ATOMIC_ACQ_REL, __HIP_MEMORY_SCOPE_AGENT);
    islast = (prev == (unsigned)(NCLS * NSEG - 1)) ? 1 : 0;
  }
  __syncthreads();
  if (islast) {
    if (tid < NCLS) {
      double d2 = 0.0;
#pragma unroll
      for (int s2 = 0; s2 < NSEG; ++s2)
        d2 += __hip_atomic_load(&partials[tid * NSEG + s2],
                                __ATOMIC_ACQUIRE, __HIP_MEMORY_SCOPE_AGENT);
      apf_s[tid] = (float)d2;
    }
    __syncthreads();
    if (tid == 0) {
      float sf = 0.0f, nf = 0.0f;
      for (int cc = 0; cc < NCLS; ++cc)
        if (gt_count[cc] > 0) { sf += apf_s[cc]; nf += 1.0f; }
      out[0] = sf / fmaxf(nf, 1.0f);
    }
  }
}

extern "C" void kernel_launch(void* const* d_in, const int* in_sizes, int n_in,
                              void* d_out, int out_size, void* d_ws, size_t ws_size,
                              hipStream_t stream) {
  const float* target = (const float*)d_in[0];
  const float* output = (const float*)d_in[1];
  int batch = in_sizes[0] / (NCELL * 30);
  int ne = batch * NCELL;
  int segimg = (((batch + NSEG - 1) / NSEG) + 15) & ~15;  // 16-image aligned

  uint8_t*  entries  = (uint8_t*)d_ws;
  size_t offA = ((size_t)ne + 255) & ~(size_t)255;
  int*      gt_count = (int*)((char*)d_ws + offA);                 // 256 B
  unsigned* totals   = (unsigned*)((char*)d_ws + offA + 256);      // 64*32*4 = 8192 B
  unsigned* counter  = (unsigned*)((char*)d_ws + offA + 256 + 8192);
  double*   partials = (double*)((char*)d_ws + offA + 8704);       // 1280*8 B

  (void)hipMemsetAsync((char*)d_ws + offA, 0, 8704, stream);
  k_per_image<<<(batch + 3) / 4, 256, 0, stream>>>(
      target, output, entries, gt_count, totals, batch, segimg);
  k_apB<<<NCLS * NSEG, 256, 0, stream>>>(
      entries, totals, gt_count, partials, counter, (float*)d_out, ne, segimg);
}

// Round 13
// 156.345 us; speedup vs baseline: 1.6271x; 1.2193x over previous
//
#include <hip/hip_runtime.h>
#include <stdint.h>

#pragma clang fp contract(off)

#define NCELL 49
#define NCLS  20
#define NSEG  16

struct Box { float x1, y1, x2, y2; };

// Bit-exact branchless sigmoid (see R9 note).
__device__ __forceinline__ float sigmoid_ref(float x) {
#pragma clang fp contract(off)
  float z = expf(-fabsf(x));
  float num = (x >= 0.0f) ? 1.0f : z;
  return num / (1.0f + z);
}

__device__ __forceinline__ float iou_box(Box a, Box b) {
#pragma clang fp contract(off)
  float lx = fmaxf(a.x1, b.x1);
  float ly = fmaxf(a.y1, b.y1);
  float rx = fminf(a.x2, b.x2);
  float ry = fminf(a.y2, b.y2);
  float w = fmaxf(rx - lx, 0.0f);
  float h = fmaxf(ry - ly, 0.0f);
  float inter = w * h;
  float aa = (a.x2 - a.x1) * (a.y2 - a.y1);
  float ab = (b.x2 - b.x1) * (b.y2 - b.y1);
  return inter / (aa + ab - inter);
}

__device__ __forceinline__ unsigned mbcnt64(unsigned long long m) {
  return __builtin_amdgcn_mbcnt_hi((unsigned)(m >> 32),
         __builtin_amdgcn_mbcnt_lo((unsigned)m, 0u));
}
#define WSYNC() __builtin_amdgcn_wave_barrier()

// 512 threads = 8 waves = 4 images x 2 roles. Role A (waves 0-3): pred
// decode + rank + NMS-low + resolve + TP + stats/store. Role B (waves 4-7):
// GT decode + full GT-match + NMS-high. Merged via LDS at two barriers.
// All math/order identical to R10 (absmax 0.0); candmask = low | high<<19.
__global__ __launch_bounds__(512) void k_per_image(
    const float* __restrict__ target, const float* __restrict__ output,
    uint8_t* __restrict__ entries, int* __restrict__ gt_count,
    unsigned* __restrict__ totals, int batch, int segimg)
{
#pragma clang fp contract(off)
  __shared__ float4   pbox[4][64];
  __shared__ int2     pcc [4][64];
  __shared__ float4   gbox[4][64];
  __shared__ int      gcv [4][64];
  __shared__ float    ctab[4][64];
  __shared__ float2   mtab[4][64];
  __shared__ unsigned candHi[4][64];

  int tid = threadIdx.x;
  int lane = tid & 63;
  int w = tid >> 6;
  int m = w & 3;                 // image slot in block
  int roleB = w >> 2;            // 0 = A (pred side), 1 = B (GT side)
  int img = blockIdx.x * 4 + m;
  bool act = img < batch;        // wave-uniform
  bool a = act && (lane < NCELL);

  int gcls = 0; bool gval = false;   // B-side registers (live across syncs)

  if (act) {
    if (roleB == 0) {
      // ---------------- role A: predictions ----------------
      float ov[30];
      if (a) {
        const float2* O2 = (const float2*)(output + (size_t)img * 1470 + lane * 30);
#pragma unroll
        for (int i = 0; i < 15; ++i) { float2 o = O2[i]; ov[2*i] = o.x; ov[2*i+1] = o.y; }
      } else {
#pragma unroll
        for (int i = 0; i < 30; ++i) ov[i] = 0.0f;
      }
      float fjx = (float)(lane % 7), fiy = (float)(lane / 7);
      float myc = -1.0f; int myk = 0; float px1 = 0, py1 = 0, px2 = 0, py2 = 0;
      if (a) {
        float s0 = sigmoid_ref(ov[4]);
        float s1 = sigmoid_ref(ov[9]);
        myc = fmaxf(s0, s1);
        int resp = (s1 > s0) ? 1 : 0;    // first max wins (sigmoid monotone)
        float x  = sigmoid_ref(ov[resp * 5 + 0]);
        float y  = sigmoid_ref(ov[resp * 5 + 1]);
        float ww = sigmoid_ref(ov[resp * 5 + 2]);
        float hh = sigmoid_ref(ov[resp * 5 + 3]);
        float obv = sigmoid_ref(ov[10]); myk = 0;
#pragma unroll
        for (int c = 1; c < NCLS; ++c) {
          float v = sigmoid_ref(ov[10 + c]);
          if (v > obv) { obv = v; myk = c; }
        }
        float cx = (x + fjx) * 64.0f, cy = (y + fiy) * 64.0f;
        float W = ww * 448.0f, H = hh * 448.0f;
        px1 = cx - W * 0.5f; py1 = cy - H * 0.5f;
        px2 = cx + W * 0.5f; py2 = cy + H * 0.5f;
      }
      ctab[m][lane] = myc;
      WSYNC();
      // stable rank (argsort(-conf), index tiebreak)
      int r = 0;
#pragma unroll
      for (int j = 0; j < NCELL; ++j) {
        float cj = ctab[m][j];
        r += (cj > myc) || (cj == myc && j < lane);
      }
      r = a ? r : lane;
      pbox[m][r] = make_float4(px1, py1, px2, py2);
      pcc[m][r]  = make_int2(myk, __float_as_int(myc));
    } else {
      // ---------------- role B: ground truth ----------------
      float tv[30];
      if (a) {
        const float2* T2 = (const float2*)(target + (size_t)img * 1470 + lane * 30);
#pragma unroll
        for (int i = 0; i < 15; ++i) { float2 t = T2[i]; tv[2*i] = t.x; tv[2*i+1] = t.y; }
      } else {
#pragma unroll
        for (int i = 0; i < 30; ++i) tv[i] = 0.0f;
      }
      float fjx = (float)(lane % 7), fiy = (float)(lane / 7);
      float tbv = tv[10];
#pragma unroll
      for (int c = 1; c < NCLS; ++c) { float v = tv[10 + c]; if (v > tbv) { tbv = v; gcls = c; } }
      gval = a && (tv[4] > 0.5f);
      float cx = (tv[0] + fjx) * 64.0f, cy = (tv[1] + fiy) * 64.0f;
      float w2 = tv[2] * 448.0f, h2 = tv[3] * 448.0f;
      gbox[m][lane] = make_float4(cx - w2 * 0.5f, cy - h2 * 0.5f,
                                  cx + w2 * 0.5f, cy + h2 * 0.5f);
      gcv[m][lane] = gcls | (gval ? 256 : 0);
    }
  }

  __syncthreads();   // sync1: pbox/pcc + gbox/gcv visible block-wide

  float4 sb4; int2 cc; Box myS; int scls = 0; float sconf = -1.0f;
  unsigned long long candLo = 0;
  if (act) {
    sb4 = pbox[m][lane];
    cc  = pcc[m][lane];
    myS.x1 = sb4.x; myS.y1 = sb4.y; myS.x2 = sb4.z; myS.y2 = sb4.w;
    scls = cc.x; sconf = __int_as_float(cc.y);

    if (roleB == 0) {
      // cand low half: i = 0..18
#pragma unroll
      for (int i = 0; i < 19; ++i) {
        float4 b4 = pbox[m][i];
        int ki = pcc[m][i].x;
        Box bi; bi.x1 = b4.x; bi.y1 = b4.y; bi.x2 = b4.z; bi.y2 = b4.w;
        float v = iou_box(myS, bi);
        bool s = a && (lane > i) && (scls == ki) && (v > 0.5f);
        candLo |= s ? (1ull << i) : 0ull;
      }
    } else {
      // full GT match (identical first-max loop g=0..48)
      float mx = -1.0f; int best = 0;
#pragma unroll
      for (int g = 0; g < NCELL; ++g) {
        float4 b4 = gbox[m][g];
        int cv = gcv[m][g];
        Box bg; bg.x1 = b4.x; bg.y1 = b4.y; bg.x2 = b4.z; bg.y2 = b4.w;
        float v = iou_box(myS, bg);
        bool upd = a && (cv & 256) && (scls == (cv & 255)) && (v > mx);
        mx = upd ? v : mx;
        best = upd ? g : best;
      }
      mtab[m][lane] = make_float2(mx, __int_as_float(best));
      // cand high half: i = 19..48 -> bit (i-19)
      unsigned ch = 0;
#pragma unroll
      for (int i = 19; i < NCELL; ++i) {
        float4 b4 = pbox[m][i];
        int ki = pcc[m][i].x;
        Box bi; bi.x1 = b4.x; bi.y1 = b4.y; bi.x2 = b4.z; bi.y2 = b4.w;
        float v = iou_box(myS, bi);
        bool s = a && (lane > i) && (scls == ki) && (v > 0.5f);
        ch |= s ? (1u << (i - 19)) : 0u;
      }
      candHi[m][lane] = ch;
    }
  }

  __syncthreads();   // sync2: mtab + candHi visible

  if (act) {
    if (roleB == 0) {
      unsigned long long candmask =
          candLo | ((unsigned long long)candHi[m][lane] << 19);

      // NMS serial resolve (branch-free select chain, A-wave ballots)
      unsigned long long sup = 0;
#pragma unroll
      for (int i = 0; i < NCELL; ++i) {
        unsigned long long bi = __ballot(((candmask >> i) & 1ull) != 0ull);
        bool keep = ((sup >> i) & 1ull) == 0ull;
        sup |= keep ? bi : 0ull;
      }
      bool vp = a && !((sup >> lane) & 1ull) && (sconf > 0.5f);

      // greedy TP assignment (reads B's mtab)
      unsigned long long vpmask = __ballot(vp);
      unsigned long long matched = 0, hits = 0;
#pragma unroll 7
      for (int i = 0; i < NCELL; ++i) {
        float2 f2 = mtab[m][i];
        float mxi = f2.x;
        int bi = __float_as_int(f2.y);
        bool hit = ((vpmask >> i) & 1ull) && (mxi > 0.5f) && !((matched >> bi) & 1ull);
        matched |= hit ? (1ull << bi) : 0ull;
        hits    |= hit ? (1ull << i)  : 0ull;
      }

      if (a) {
        entries[(size_t)img * NCELL + lane] =
            (uint8_t)(scls | (vp ? 32 : 0) | (((hits >> lane) & 1ull) ? 64 : 0));
      }

      // totals stats (valid,tp) per (segment,class)
      int seg = img / segimg;
      unsigned pkt = 0;
#pragma unroll 1
      for (int c = 0; c < NCLS; ++c) {
        unsigned long long pm = __ballot(a && (scls == c));
        if (lane == c)
          pkt = ((unsigned)__popcll(pm & vpmask) << 16) |
                 (unsigned)__popcll(pm & hits);
      }
      if (lane < NCLS && pkt) atomicAdd(&totals[seg * 32 + lane], pkt);
    } else {
      // gt_count stats (B-wave ballots)
      int gcnt = 0;
#pragma unroll 1
      for (int c = 0; c < NCLS; ++c) {
        unsigned long long gm = __ballot(gval && (gcls == c));
        if (lane == c) gcnt = (int)__popcll(gm);
      }
      if (lane < NCLS && gcnt) atomicAdd(&gt_count[lane], gcnt);
    }
  }
}

__device__ __forceinline__ unsigned match_mask(unsigned w, unsigned wantx4) {
  unsigned y = (w & 0x3f3f3f3fu) ^ wantx4;
  return ~(y + 0x7f7f7f7fu) & 0x80808080u;
}

__device__ __forceinline__ uint4 load_tile(const uint8_t* entries, int e, int e1, int ne) {
  uint4 w4 = make_uint4(0, 0, 0, 0);
  if (e < e1) {
    int p = e << 4;
    if (p + 16 <= ne) {
      w4 = *(const uint4*)(entries + p);
    } else {
      unsigned ws[4] = {0, 0, 0, 0};
      for (int k = 0; k < ne - p; ++k)
        ws[k >> 2] |= ((unsigned)entries[p + k]) << (8 * (k & 3));
      w4.x = ws[0]; w4.y = ws[1]; w4.z = ws[2]; w4.w = ws[3];
    }
  }
  return w4;
}

// R10's apB (NSEG=16; best-measured tail) + lane-parallel totals prefix.
__global__ __launch_bounds__(256) void k_apB(
    const uint8_t* __restrict__ entries, const unsigned* __restrict__ totals,
    const int* __restrict__ gt_count, double* __restrict__ partials,
    unsigned* __restrict__ counter, float* __restrict__ out,
    int ne, int segimg)
{
#pragma clang fp contract(off)
  int c = blockIdx.x / NSEG, s = blockIdx.x % NSEG;
  int tid = threadIdx.x, wid = tid >> 6, lane = tid & 63;
  float g2 = (float)gt_count[c] + 1e-6f;
  unsigned wantx4 = (32u + (unsigned)c) * 0x01010101u;

  int nel = (ne + 15) >> 4;
  int segel = segimg * NCELL / 16;
  int se0 = s * segel; if (se0 > nel) se0 = nel;
  int se1 = se0 + segel; if (se1 > nel) se1 = nel;
  int elw = (se1 > se0) ? ((se1 - se0 + 3) >> 2) : 0;
  int e0 = se0 + wid * elw; if (e0 > se1) e0 = se1;
  int e1 = e0 + elw; if (e1 > se1) e1 = se1;
  int ntile = (e1 > e0) ? ((e1 - e0 + 63) >> 6) : 0;

  // global prefix: lane-parallel load + wave reduce (exact ints)
  unsigned long long pk = 0;
  if (lane < s) {
    unsigned t2 = totals[lane * 32 + c];
    pk = ((unsigned long long)(t2 >> 16) << 32) | (unsigned long long)(t2 & 0xffffu);
  }
#pragma unroll
  for (int d = 1; d < 64; d <<= 1) pk += __shfl_xor(pk, d, 64);
  unsigned Jrun = (unsigned)(pk >> 32), Trun = (unsigned)(pk & 0xffffffffull);

  unsigned mv = 0, mt = 0;
  for (int t = 0; t < ntile; ++t) {
    uint4 w4 = load_tile(entries, e0 + t * 64 + lane, e1, ne);
    unsigned wsv[4] = {w4.x, w4.y, w4.z, w4.w};
#pragma unroll
    for (int q = 0; q < 4; ++q) {
      unsigned m = match_mask(wsv[q], wantx4);
      mv += __popc(m);
      mt += __popc(m & (wsv[q] << 1));
    }
  }
  unsigned long long tot = ((unsigned long long)mv << 32) | (unsigned long long)mt;
#pragma unroll
  for (int d = 1; d < 64; d <<= 1) tot += __shfl_xor(tot, d, 64);
  __shared__ unsigned long long wt[4];
  __shared__ double wacc[4];
  __shared__ int islast;
  __shared__ float apf_s[NCLS];
  if (lane == 0) wt[wid] = tot;
  __syncthreads();
  for (int w2 = 0; w2 < wid; ++w2) {
    Jrun += (unsigned)(wt[w2] >> 32);
    Trun += (unsigned)(wt[w2] & 0xffffffffull);
  }

  double acc = 0.0;
  for (int t = 0; t < ntile; ++t) {
    int e = e0 + t * 64 + lane;
    int p = e << 4;
    uint4 w4 = load_tile(entries, e, e1, ne);
    unsigned wsv[4] = {w4.x, w4.y, w4.z, w4.w};
    unsigned mm[4], tm[4];
    unsigned cv = 0, ct = 0;
#pragma unroll
    for (int q = 0; q < 4; ++q) {
      unsigned m = match_mask(wsv[q], wantx4);
      mm[q] = m; tm[q] = m & (wsv[q] << 1);
      cv += __popc(m); ct += __popc(tm[q]);
    }
    unsigned jexcl = 0, texcl = 0, jtt = 0, ttt = 0;
#pragma unroll
    for (int b = 0; b < 5; ++b) {
      unsigned long long mj = __ballot(((cv >> b) & 1u) != 0u);
      unsigned long long mk = __ballot(((ct >> b) & 1u) != 0u);
      jexcl += mbcnt64(mj) << b;
      texcl += mbcnt64(mk) << b;
      jtt   += (unsigned)__popcll(mj) << b;
      ttt   += (unsigned)__popcll(mk) << b;
    }
    unsigned jr = Jrun + jexcl;
    unsigned tr = Trun + texcl;
#pragma unroll
    for (int q = 0; q < 4; ++q) {
      unsigned m = mm[q];
      while (m) {
        unsigned bit = (unsigned)__builtin_ctz(m);
        m &= m - 1;
        ++jr;
        if (tm[q] & (1u << bit)) {
          ++tr;
          int pos = p + 4 * q + (int)(bit >> 3);
          float ft = (float)tr, fj = (float)jr;
          float r_cur  = ft / g2;
          float r_prev = (ft - 1.0f) / g2;
          float p_cur  = ft / (fj + 1e-6f);
          float p_prev = (pos == 0) ? 1.0f
                                    : (ft - 1.0f) / ((fj - 1.0f) + 1e-6f);
          acc += (double)((r_cur - r_prev) * (p_cur + p_prev) * 0.5f);
        }
      }
    }
    Jrun += jtt;
    Trun += ttt;
  }

  for (int d = 32; d > 0; d >>= 1) acc += __shfl_down(acc, d, 64);
  if (lane == 0) wacc[wid] = acc;
  __syncthreads();
  if (tid == 0) {
    double bp = wacc[0] + wacc[1] + wacc[2] + wacc[3];
    __hip_atomic_store(&partials[blockIdx.x], bp,
                       __ATOMIC_RELEASE, __HIP_MEMORY_SCOPE_AGENT);
    unsigned prev = __hip_atomic_fetch_add(counter, 1u,
                       __ATOMIC_ACQ_REL, __HIP_MEMORY_SCOPE_AGENT);
    islast = (prev == (unsigned)(NCLS * NSEG - 1)) ? 1 : 0;
  }
  __syncthreads();
  if (islast) {
    if (tid < NCLS) {
      double d2 = 0.0;
#pragma unroll
      for (int s2 = 0; s2 < NSEG; ++s2)
        d2 += __hip_atomic_load(&partials[tid * NSEG + s2],
                                __ATOMIC_ACQUIRE, __HIP_MEMORY_SCOPE_AGENT);
      apf_s[tid] = (float)d2;
    }
    __syncthreads();
    if (tid == 0) {
      float sf = 0.0f, nf = 0.0f;
      for (int cc = 0; cc < NCLS; ++cc)
        if (gt_count[cc] > 0) { sf += apf_s[cc]; nf += 1.0f; }
      out[0] = sf / fmaxf(nf, 1.0f);
    }
  }
}

extern "C" void kernel_launch(void* const* d_in, const int* in_sizes, int n_in,
                              void* d_out, int out_size, void* d_ws, size_t ws_size,
                              hipStream_t stream) {
  const float* target = (const float*)d_in[0];
  const float* output = (const float*)d_in[1];
  int batch = in_sizes[0] / (NCELL * 30);
  int ne = batch * NCELL;
  int segimg = (((batch + NSEG - 1) / NSEG) + 15) & ~15;  // 16-image aligned

  uint8_t*  entries  = (uint8_t*)d_ws;
  size_t offA = ((size_t)ne + 255) & ~(size_t)255;
  int*      gt_count = (int*)((char*)d_ws + offA);                 // 256 B
  unsigned* totals   = (unsigned*)((char*)d_ws + offA + 256);      // 2048 B
  unsigned* counter  = (unsigned*)((char*)d_ws + offA + 256 + 2048);
  double*   partials = (double*)((char*)d_ws + offA + 4096);       // 2560 B

  (void)hipMemsetAsync((char*)d_ws + offA, 0, 4096, stream);
  k_per_image<<<(batch + 3) / 4, 512, 0, stream>>>(
      target, output, entries, gt_count, totals, batch, segimg);
  k_apB<<<NCLS * NSEG, 256, 0, stream>>>(
      entries, totals, gt_count, partials, counter, (float*)d_out, ne, segimg);
}